// Round 7
// baseline (515.886 us; speedup 1.0000x reference)
//
#include <hip/hip_runtime.h>
#include <hip/hip_fp16.h>
#include <cstdint>

typedef _Float16 h16;
typedef _Float16 half8 __attribute__((ext_vector_type(8)));
typedef float floatx4 __attribute__((ext_vector_type(4)));

#define T_SZ 60
#define H_SZ 128
#define NB_FC1 7680   // T*H = 60*128

#define LOG2E  1.44269504088896340736f
#define LOG2E2 2.88539008177792681472f

// sigmoid / tanh via v_exp_f32 + v_rcp_f32 (no IEEE-div sequence).
__device__ __forceinline__ float sigm(float x) {
    float e = __builtin_amdgcn_exp2f(x * -LOG2E);
    return __builtin_amdgcn_rcpf(1.0f + e);
}
__device__ __forceinline__ float tanh_fast(float x) {
    float e = __builtin_amdgcn_exp2f(x * LOG2E2);   // exp(2x)
    return 1.0f - 2.0f * __builtin_amdgcn_rcpf(e + 1.0f);
}

// MFMA with the B (weight) operand pinned to AGPRs: on gfx950 A/B may come
// from VGPR or AGPR. Weights are written once and only read by MFMA, so the
// "a" constraint parks them in the otherwise-idle AGPR half of the unified
// register file (accum_offset=64 split at the 128-reg/wave budget).
// D==C tied ("+v"); dependent MFMA D->SrcC chains need 0 wait states.
__device__ __forceinline__ void mfma_aw(floatx4& c, half8 a, half8 b) {
    asm("v_mfma_f32_16x16x32_f16 %0, %1, %2, %0" : "+v"(c) : "v"(a), "a"(b));
}

// ---------------------------------------------------------------------------
// Fused LSTM layer, gate-split: block = 16 batch rows x all 60 timesteps,
// grid 256, 1024 threads (16 waves -> 4 waves/SIMD issue overlap, 1 block/CU,
// 128 total regs/wave: ~60 arch VGPR + 48/64 AGPR of weights -> no spill).
// Wave w: role = w>>3 (0: gates i,f + cell update; 1: gates g,o), col-tile
// wg = w&7. Role 1 passes tanh(g), sigm(o) as fp16 via LDS exchange.
// h history in an 8-slot LDS ring, flushed every 8 steps with wide stores.
// x prefetched 1 step ahead; f32->f16 conversion at consume point.
// Manual hazard guards around inline-asm MFMA clusters (s_nop 2 pre for
// VALU->MFMA SrcA/C, s_nop 7 x2 post for MFMA->VALU ~11 wait states).
// ---------------------------------------------------------------------------
template<int INDIM, bool IN_F32>
__global__ __launch_bounds__(1024, 4)
void lstm_layer(const void* __restrict__ in_v,
                const float* __restrict__ W_ih,
                const float* __restrict__ W_hh,
                const float* __restrict__ b_ih,
                const float* __restrict__ b_hh,
                h16* __restrict__ h_out)
{
    constexpr int KT_IN = INDIM / 32;
    __shared__ __align__(16) h16 hist[8][16][H_SZ];   // 32 KB swizzled ring
    __shared__ __align__(16) h16 exch[2][8][64][8];   // 16 KB gate exchange

    const int tid  = threadIdx.x;
    const int w    = tid >> 6;
    const int role = w >> 3;      // 0: i,f + cell; 1: g,o
    const int wg   = w & 7;       // col-tile
    const int lane = tid & 63;
    const int lrow = lane & 15;   // A-row / B-col within tile
    const int lgrp = lane >> 4;   // k-group
    const size_t base_row = (size_t)blockIdx.x * 16;

    // ---- register-resident B-fragments (2 gate-tiles per wave, AGPR) -------
    half8 wf_a[2][KT_IN];   // only used as "a" operand -> lives in AGPRs
    half8 wf_h[2][4];       // only used as "a" operand -> lives in AGPRs
    float bias[2];

    #pragma unroll
    for (int q = 0; q < 2; ++q) {
        const int qg = role * 2 + q;                // 0:i 1:f 2:g 3:o
        const int n  = (wg + 8 * qg) * 16 + lrow;   // gate row (0..511)
        bias[q] = b_ih[n] + b_hh[n];
        #pragma unroll
        for (int kt = 0; kt < KT_IN; ++kt) {
            const float* p = W_ih + (size_t)n * INDIM + kt * 32 + lgrp * 8;
            half8 v;
            #pragma unroll
            for (int j = 0; j < 8; ++j) v[j] = (h16)p[j];
            wf_a[q][kt] = v;
        }
        #pragma unroll
        for (int kt = 0; kt < 4; ++kt) {
            const float* p = W_hh + (size_t)n * H_SZ + kt * 32 + lgrp * 8;
            half8 v;
            #pragma unroll
            for (int j = 0; j < 8; ++j) v[j] = (h16)p[j];
            wf_h[q][kt] = v;
        }
    }

    const float* inF = (const float*)in_v;
    const h16*   inH = (const h16*)in_v;

    // single x prefetch slot (distance 1)
    floatx4 raw[KT_IN][2];
    half8   xs[KT_IN];

    auto load_x = [&](int t) {
        #pragma unroll
        for (int kt = 0; kt < KT_IN; ++kt) {
            if constexpr (IN_F32) {
                const float* p = inF + ((base_row + lrow) * T_SZ + t) * INDIM + kt * 32 + lgrp * 8;
                raw[kt][0] = *(const floatx4*)(p);
                raw[kt][1] = *(const floatx4*)(p + 4);
            } else {
                xs[kt] = *(const half8*)(inH + ((base_row + lrow) * T_SZ + t) * INDIM + kt * 32 + lgrp * 8);
            }
        }
    };

    load_x(0);

    floatx4 c4 = {0.f, 0.f, 0.f, 0.f};   // role 0 only
    const int colW = 16 * wg + lrow;      // this lane's h-column

    auto flush = [&](int t) {
        half8 vals[2];
        int   t_loc[2], row[2], cg[2];
        #pragma unroll
        for (int s = 0; s < 2; ++s) {
            const int u = tid + 1024 * s;       // 0..2047
            t_loc[s] = u >> 8;
            row[s]   = (u >> 4) & 15;
            cg[s]    = u & 15;
            vals[s] = *(const half8*)&hist[t_loc[s]][row[s]][(cg[s] * 8) ^ ((row[s] & 7) << 3)];
        }
        #pragma unroll
        for (int s = 0; s < 2; ++s) {
            const int tg = t - ((t - t_loc[s]) & 7);
            *(half8*)(h_out + ((base_row + row[s]) * T_SZ + tg) * H_SZ + cg[s] * 8) = vals[s];
        }
        // no barrier needed: barrier #1 of the next step orders these reads
        // against the next ring write.
    };

    #pragma unroll 1
    for (int t = 0; t < T_SZ; ++t) {
        floatx4 acc0 = {bias[0], bias[0], bias[0], bias[0]};
        floatx4 acc1 = {bias[1], bias[1], bias[1], bias[1]};

        // ---- phase A: x-MFMAs first (x already in regs) -------------------
        if constexpr (IN_F32) {
            half8 xf[KT_IN];
            #pragma unroll
            for (int kt = 0; kt < KT_IN; ++kt) {
                half8 v;
                #pragma unroll
                for (int j = 0; j < 4; ++j) { v[j] = (h16)raw[kt][0][j]; v[4 + j] = (h16)raw[kt][1][j]; }
                xf[kt] = v;
            }
            // pre-guard: orders cvt -> s_nop 2 -> MFMA (VALU->MFMA SrcA/C)
            if constexpr (KT_IN == 2)
                asm volatile("s_nop 2" : "+v"(acc0), "+v"(acc1), "+v"(xf[0]), "+v"(xf[1]));
            else
                asm volatile("s_nop 2" : "+v"(acc0), "+v"(acc1), "+v"(xf[0]), "+v"(xf[KT_IN - 1]));
            #pragma unroll
            for (int kt = 0; kt < KT_IN; ++kt) {
                mfma_aw(acc0, xf[kt], wf_a[0][kt]);
                mfma_aw(acc1, xf[kt], wf_a[1][kt]);
            }
            if (t + 1 < T_SZ) load_x(t + 1);
        } else {
            // xs comes from global loads (vmcnt-guarded); guard SrcC only
            asm volatile("s_nop 2" : "+v"(acc0), "+v"(acc1));
            #pragma unroll
            for (int kt = 0; kt < KT_IN; ++kt) {
                mfma_aw(acc0, xs[kt], wf_a[0][kt]);
                mfma_aw(acc1, xs[kt], wf_a[1][kt]);
            }
            if (t + 1 < T_SZ) load_x(t + 1);
        }

        // ---- h-MFMAs: read one fragment at a time (lower peak liveness) ---
        if (t > 0) {
            const h16* hb = &hist[(t + 7) & 7][0][0];
            #pragma unroll
            for (int kt = 0; kt < 4; ++kt) {
                const int col0 = kt * 32 + lgrp * 8;
                const half8 hfk = *(const half8*)(hb + lrow * H_SZ + (col0 ^ ((lrow & 7) << 3)));
                mfma_aw(acc0, hfk, wf_h[0][kt]);
                mfma_aw(acc1, hfk, wf_h[1][kt]);
            }
        }

        // post-guard: MFMA write -> VALU read needs ~11 wait states
        asm volatile("s_nop 7\n\ts_nop 7" : "+v"(acc0), "+v"(acc1));

        // ---- phase B: role-local activations ------------------------------
        floatx4 g0, g1;             // role0: gi,gf ; role1: gg,go
        if (role == 1) {
            half8 pk;
            #pragma unroll
            for (int r = 0; r < 4; ++r) {
                const float gg = tanh_fast(acc0[r]);
                const float go = sigm(acc1[r]);
                pk[r]     = (h16)gg;
                pk[4 + r] = (h16)go;
            }
            *(half8*)&exch[t & 1][wg][lane][0] = pk;
        } else {
            #pragma unroll
            for (int r = 0; r < 4; ++r) {
                g0[r] = sigm(acc0[r]);
                g1[r] = sigm(acc1[r]);
            }
        }

        asm volatile("s_waitcnt lgkmcnt(0)" ::: "memory");
        __builtin_amdgcn_s_barrier();       // barrier #1: exchange ready
        asm volatile("" ::: "memory");

        // ---- phase C: role 0 cell update + ring write ---------------------
        if (role == 0) {
            const half8 pk = *(const half8*)&exch[t & 1][wg][lane][0];
            h16* hb2 = &hist[t & 7][0][0];
            #pragma unroll
            for (int r = 0; r < 4; ++r) {
                const float gg = (float)pk[r];
                const float go = (float)pk[4 + r];
                const float cc = g1[r] * c4[r] + g0[r] * gg;
                c4[r] = cc;
                const h16 hh = (h16)(go * tanh_fast(cc));
                const int rowW = lgrp * 4 + r;
                hb2[rowW * H_SZ + (colW ^ ((rowW & 7) << 3))] = hh;
            }
        }

        asm volatile("s_waitcnt lgkmcnt(0)" ::: "memory");
        __builtin_amdgcn_s_barrier();       // barrier #2: h(t) ready
        asm volatile("" ::: "memory");

        if (((t & 7) == 7) || (t == T_SZ - 1)) flush(t);
    }
}

// ---------------------------------------------------------------------------
// Wc = W_fc2 @ W_fc1  ->  [60, 7680] fp16   (folded linear head)
// ---------------------------------------------------------------------------
__global__ __launch_bounds__(256, 2)
void wc_kernel(const float* __restrict__ W_fc1,   // [512][7680]
               const float* __restrict__ W_fc2,   // [60][512]
               h16* __restrict__ Wc)              // [60][7680]
{
    __shared__ __align__(16) float lds1[64 * 16];   // [k][j]
    __shared__ __align__(16) float lds2[64 * 68];   // [k][m] (padded)
    const int tid = threadIdx.x;
    const int j0  = blockIdx.x * 16;
    const int jt  = tid & 15;
    const int mt  = tid >> 4;          // m-set {4mt .. 4mt+3}
    float acc[4] = {0.f, 0.f, 0.f, 0.f};

    for (int kc = 0; kc < 512; kc += 64) {
        __syncthreads();
        for (int i = tid; i < 64 * 16; i += 256) {
            const int k = i >> 4, j = i & 15;
            lds1[k * 16 + j] = W_fc1[(size_t)(kc + k) * NB_FC1 + j0 + j];
        }
        for (int i = tid; i < 64 * 64; i += 256) {
            const int k = i & 63, m = i >> 6;
            lds2[k * 68 + m] = (m < 60) ? W_fc2[m * 512 + kc + k] : 0.f;
        }
        __syncthreads();
        for (int k = 0; k < 64; ++k) {
            const float v1 = lds1[k * 16 + jt];
            const floatx4 v2 = *(const floatx4*)&lds2[k * 68 + 4 * mt];
            acc[0] += v2[0] * v1; acc[1] += v2[1] * v1;
            acc[2] += v2[2] * v1; acc[3] += v2[3] * v1;
        }
    }
    #pragma unroll
    for (int s = 0; s < 4; ++s) {
        const int m = 4 * mt + s;
        if (m < 60) Wc[(size_t)m * NB_FC1 + j0 + jt] = (h16)acc[s];
    }
}

// bc = W_fc2 @ b_fc1 + b_fc2   [60] fp32
__global__ void bc_kernel(const float* __restrict__ W_fc2, const float* __restrict__ b_fc1,
                          const float* __restrict__ b_fc2, float* __restrict__ bc)
{
    const int m = blockIdx.x, t = threadIdx.x;
    float p = W_fc2[m * 512 + t] * b_fc1[t] + W_fc2[m * 512 + 256 + t] * b_fc1[256 + t];
    #pragma unroll
    for (int off = 1; off < 64; off <<= 1) p += __shfl_xor(p, off);
    __shared__ float sred[4];
    if ((t & 63) == 0) sred[t >> 6] = p;
    __syncthreads();
    if (t == 0) bc[m] = sred[0] + sred[1] + sred[2] + sred[3] + b_fc2[m];
}

// ---------------------------------------------------------------------------
// out[B,60] = h2flat[B,7680] @ Wc^T + bc.
// ---------------------------------------------------------------------------
__global__ __launch_bounds__(256, 2)
void fc_kernel(const h16* __restrict__ h2,
               const h16* __restrict__ Wc,
               const float* __restrict__ bcv,
               float* __restrict__ out)
{
    __shared__ float red[4][4][16][16];   // [wave][q][row][col]
    const int tid = threadIdx.x;
    const int w = tid >> 6, lane = tid & 63, lrow = lane & 15, lgrp = lane >> 4;
    const size_t base_row = (size_t)blockIdx.x * 16;

    floatx4 acc[4];
    #pragma unroll
    for (int q = 0; q < 4; ++q) acc[q] = floatx4{0.f, 0.f, 0.f, 0.f};

    const h16* arow = h2 + (base_row + lrow) * NB_FC1;
    for (int i = 0; i < 60; ++i) {
        const int kt = w * 60 + i;
        const int k0 = kt * 32 + lgrp * 8;
        const half8 a = *(const half8*)(arow + k0);
        #pragma unroll
        for (int q = 0; q < 4; ++q) {
            const int n = q * 16 + lrow;
            half8 b = 0;
            if (n < 60) b = *(const half8*)(Wc + (size_t)n * NB_FC1 + k0);
            acc[q] = __builtin_amdgcn_mfma_f32_16x16x32_f16(a, b, acc[q], 0, 0, 0);
        }
    }
    #pragma unroll
    for (int q = 0; q < 4; ++q)
        #pragma unroll
        for (int r = 0; r < 4; ++r)
            red[w][q][lgrp * 4 + r][lrow] = acc[q][r];
    __syncthreads();

    #pragma unroll
    for (int s = 0; s < 4; ++s) {
        const int idx = tid + 256 * s;
        const int row = idx >> 6, col = idx & 63;
        if (col < 60) {
            const int q = col >> 4, cin = col & 15;
            const float v = red[0][q][row][cin] + red[1][q][row][cin]
                          + red[2][q][row][cin] + red[3][q][row][cin];
            out[(base_row + row) * 60 + col] = v + bcv[col];
        }
    }
}

extern "C" void kernel_launch(void* const* d_in, const int* in_sizes, int n_in,
                              void* d_out, int out_size, void* d_ws, size_t ws_size,
                              hipStream_t stream)
{
    const float* X      = (const float*)d_in[0];
    const float* W_ih1  = (const float*)d_in[1];
    const float* W_hh1  = (const float*)d_in[2];
    const float* b_ih1  = (const float*)d_in[3];
    const float* b_hh1  = (const float*)d_in[4];
    const float* W_ih2  = (const float*)d_in[5];
    const float* W_hh2  = (const float*)d_in[6];
    const float* b_ih2  = (const float*)d_in[7];
    const float* b_hh2  = (const float*)d_in[8];
    const float* W_fc1  = (const float*)d_in[9];
    const float* b_fc1  = (const float*)d_in[10];
    const float* W_fc2  = (const float*)d_in[11];
    const float* b_fc2  = (const float*)d_in[12];

    // workspace layout: h1 (63MB fp16) | h2 (63MB fp16) | Wc (0.92MB fp16) | bc
    h16* h1 = (h16*)d_ws;
    h16* h2 = h1 + (size_t)4096 * NB_FC1;
    h16* Wc = h2 + (size_t)4096 * NB_FC1;
    float* bc = (float*)(Wc + (size_t)60 * NB_FC1);

    wc_kernel<<<480, 256, 0, stream>>>(W_fc1, W_fc2, Wc);
    bc_kernel<<<60, 256, 0, stream>>>(W_fc2, b_fc1, b_fc2, bc);
    lstm_layer<64,  true ><<<256, 1024, 0, stream>>>((const void*)X,  W_ih1, W_hh1, b_ih1, b_hh1, h1);
    lstm_layer<128, false><<<256, 1024, 0, stream>>>((const void*)h1, W_ih2, W_hh2, b_ih2, b_hh2, h2);
    fc_kernel<<<256, 256, 0, stream>>>(h2, Wc, bc, (float*)d_out);
}

// Round 8
// 266.145 us; speedup vs baseline: 1.9384x; 1.9384x over previous
//
#include <hip/hip_runtime.h>
#include <hip/hip_fp16.h>
#include <cstdint>

typedef _Float16 h16;
typedef _Float16 half8 __attribute__((ext_vector_type(8)));
typedef float floatx4 __attribute__((ext_vector_type(4)));

#define T_SZ 60
#define H_SZ 128
#define NB_FC1 7680   // T*H = 60*128

#define LOG2E  1.44269504088896340736f
#define LOG2E2 2.88539008177792681472f

// sigmoid / tanh via v_exp_f32 + v_rcp_f32 (no IEEE-div sequence).
__device__ __forceinline__ float sigm(float x) {
    float e = __builtin_amdgcn_exp2f(x * -LOG2E);
    return __builtin_amdgcn_rcpf(1.0f + e);
}
__device__ __forceinline__ float tanh_fast(float x) {
    float e = __builtin_amdgcn_exp2f(x * LOG2E2);   // exp(2x)
    return 1.0f - 2.0f * __builtin_amdgcn_rcpf(e + 1.0f);
}

// ---------------------------------------------------------------------------
// Fused LSTM layer (R4 structure + cross-step software pipelining):
// block = 16 batch rows x 60 timesteps, grid 256, 512 threads (8 waves,
// 1 block/CU, uncapped 256-reg budget -> no spill; occupancy is structural).
// Wave w owns gate n-tiles {w, 8+w, 16+w, 24+w} (i,f,g,o for h-cols
// [16w,16w+16)) -> cell update is pure per-lane register math.
// PIPELINE: the x-part of step t+1 (bias seed + x-MFMAs into accN) runs in
// step t's activation/store phase (independent of h(t), different pipes),
// so the post-barrier critical path is only hf-read -> h-MFMA -> act -> write.
// Double accumulators accA/accB alternate via 2-unrolled loop (static idx).
// h history in a 16-slot LDS ring (64KB): flush every 8 steps reads one half
// while writes go to the other half -> WAR distance 8 barriers (fixes the
// 8-slot ring's same-window read/write race). 1 barrier per step, raw
// s_barrier with lgkmcnt-only wait (x loads stay in flight across it).
// ---------------------------------------------------------------------------
template<int INDIM, bool IN_F32>
__global__ __launch_bounds__(512, 1)
void lstm_layer(const void* __restrict__ in_v,
                const float* __restrict__ W_ih,
                const float* __restrict__ W_hh,
                const float* __restrict__ b_ih,
                const float* __restrict__ b_hh,
                h16* __restrict__ h_out)
{
    constexpr int KT_IN = INDIM / 32;
    __shared__ __align__(16) h16 hist[16][16][H_SZ];   // 64 KB swizzled ring

    const int tid  = threadIdx.x;
    const int w    = tid >> 6;
    const int lane = tid & 63;
    const int lrow = lane & 15;   // A-row / B-col within tile
    const int lgrp = lane >> 4;   // k-group
    const size_t base_row = (size_t)blockIdx.x * 16;

    // -------- register-resident B-fragments of W_ih / W_hh (fp32 -> fp16) ----
    half8 wf_in[4][KT_IN];
    half8 wf_hh[4][4];
    float bias[4];

    #pragma unroll
    for (int q = 0; q < 4; ++q) {
        const int n = (w + 8 * q) * 16 + lrow;      // gate row (0..511)
        bias[q] = b_ih[n] + b_hh[n];
        #pragma unroll
        for (int kt = 0; kt < KT_IN; ++kt) {
            const float* p = W_ih + (size_t)n * INDIM + kt * 32 + lgrp * 8;
            half8 v;
            #pragma unroll
            for (int j = 0; j < 8; ++j) v[j] = (h16)p[j];
            wf_in[q][kt] = v;
        }
        #pragma unroll
        for (int kt = 0; kt < 4; ++kt) {
            const float* p = W_hh + (size_t)n * H_SZ + kt * 32 + lgrp * 8;
            half8 v;
            #pragma unroll
            for (int j = 0; j < 8; ++j) v[j] = (h16)p[j];
            wf_hh[q][kt] = v;
        }
    }

    const float* inF = (const float*)in_v;
    const h16*   inH = (const h16*)in_v;

    // single x slot; loaded ~1 full step before consumption
    floatx4 raw[KT_IN][2];
    half8   xs[KT_IN];

    auto load_x = [&](int t) {
        #pragma unroll
        for (int kt = 0; kt < KT_IN; ++kt) {
            if constexpr (IN_F32) {
                const float* p = inF + ((base_row + lrow) * T_SZ + t) * INDIM + kt * 32 + lgrp * 8;
                raw[kt][0] = *(const floatx4*)(p);
                raw[kt][1] = *(const floatx4*)(p + 4);
            } else {
                xs[kt] = *(const half8*)(inH + ((base_row + lrow) * T_SZ + t) * INDIM + kt * 32 + lgrp * 8);
            }
        }
    };

    auto get_x = [&](half8 (&xf)[KT_IN]) {   // consume-point f32->f16 cvt
        #pragma unroll
        for (int kt = 0; kt < KT_IN; ++kt) {
            if constexpr (IN_F32) {
                half8 v;
                #pragma unroll
                for (int j = 0; j < 4; ++j) { v[j] = (h16)raw[kt][0][j]; v[4 + j] = (h16)raw[kt][1][j]; }
                xf[kt] = v;
            } else {
                xf[kt] = xs[kt];
            }
        }
    };

    floatx4 c4 = {0.f, 0.f, 0.f, 0.f};
    const int colW = 16 * w + lrow;   // this lane's h-column

    auto flush = [&](int t) {   // stores h(t-7..t); ring half disjoint from next writes
        half8 vals[4];
        int   time[4], row[4], cg[4];
        #pragma unroll
        for (int s = 0; s < 4; ++s) {
            const int u = tid + 512 * s;        // 0..2047
            time[s] = t - 7 + (u >> 8);
            row[s]  = (u >> 4) & 15;
            cg[s]   = u & 15;
            vals[s] = *(const half8*)&hist[time[s] & 15][row[s]][(cg[s] * 8) ^ ((row[s] & 7) << 3)];
        }
        #pragma unroll
        for (int s = 0; s < 4; ++s)
            *(half8*)(h_out + ((base_row + row[s]) * T_SZ + time[s]) * H_SZ + cg[s] * 8) = vals[s];
    };

    // -------- prologue: accA = bias + x-part(0); prefetch x(1) ---------------
    floatx4 accA[4], accB[4];
    load_x(0);
    {
        half8 xf[KT_IN];
        get_x(xf);
        #pragma unroll
        for (int q = 0; q < 4; ++q) accA[q] = floatx4{bias[q], bias[q], bias[q], bias[q]};
        #pragma unroll
        for (int kt = 0; kt < KT_IN; ++kt)
            #pragma unroll
            for (int q = 0; q < 4; ++q)
                accA[q] = __builtin_amdgcn_mfma_f32_16x16x32_f16(xf[kt], wf_in[q][kt], accA[q], 0, 0, 0);
        load_x(1);
    }

    auto step = [&](int t, floatx4 (&accC)[4], floatx4 (&accN)[4]) {
        // ---- h-MFMAs on the critical path (accC already holds bias+x(t)) ---
        if (t > 0) {
            const h16* hb = &hist[(t - 1) & 15][0][0];
            half8 hf[4];
            #pragma unroll
            for (int kt = 0; kt < 4; ++kt) {
                const int col0 = kt * 32 + lgrp * 8;
                hf[kt] = *(const half8*)(hb + lrow * H_SZ + (col0 ^ ((lrow & 7) << 3)));
            }
            #pragma unroll
            for (int kt = 0; kt < 4; ++kt)
                #pragma unroll
                for (int q = 0; q < 4; ++q)
                    accC[q] = __builtin_amdgcn_mfma_f32_16x16x32_f16(hf[kt], wf_hh[q][kt], accC[q], 0, 0, 0);
        }

        // ---- activations + cell update + ring write ------------------------
        h16 hcast[4];
        #pragma unroll
        for (int r = 0; r < 4; ++r) {
            const float gi = sigm(accC[0][r]);
            const float gf = sigm(accC[1][r]);
            const float gg = tanh_fast(accC[2][r]);
            const float go = sigm(accC[3][r]);
            const float cc = gf * c4[r] + gi * gg;
            c4[r] = cc;
            hcast[r] = (h16)(go * tanh_fast(cc));
        }
        h16* hb2 = &hist[t & 15][0][0];
        #pragma unroll
        for (int r = 0; r < 4; ++r) {
            const int rowW = lgrp * 4 + r;
            hb2[rowW * H_SZ + (colW ^ ((rowW & 7) << 3))] = hcast[r];
        }

        // ---- pipelined x-part of step t+1 (independent of h(t)) ------------
        if (t + 1 < T_SZ) {
            half8 xf[KT_IN];
            get_x(xf);
            #pragma unroll
            for (int q = 0; q < 4; ++q) accN[q] = floatx4{bias[q], bias[q], bias[q], bias[q]};
            #pragma unroll
            for (int kt = 0; kt < KT_IN; ++kt)
                #pragma unroll
                for (int q = 0; q < 4; ++q)
                    accN[q] = __builtin_amdgcn_mfma_f32_16x16x32_f16(xf[kt], wf_in[q][kt], accN[q], 0, 0, 0);
            if (t + 2 < T_SZ) load_x(t + 2);
        }

        // raw barrier: wait only on LDS (x loads stay in flight)
        asm volatile("s_waitcnt lgkmcnt(0)" ::: "memory");
        __builtin_amdgcn_s_barrier();
        asm volatile("" ::: "memory");

        if (((t & 7) == 7) || (t == T_SZ - 1)) flush(t);
    };

    #pragma unroll 1
    for (int tt = 0; tt < T_SZ; tt += 2) {
        step(tt,     accA, accB);
        step(tt + 1, accB, accA);
    }
}

// ---------------------------------------------------------------------------
// Wc = W_fc2 @ W_fc1  ->  [60, 7680] fp16   (folded linear head)
// ---------------------------------------------------------------------------
__global__ __launch_bounds__(256, 2)
void wc_kernel(const float* __restrict__ W_fc1,   // [512][7680]
               const float* __restrict__ W_fc2,   // [60][512]
               h16* __restrict__ Wc)              // [60][7680]
{
    __shared__ __align__(16) float lds1[64 * 16];   // [k][j]
    __shared__ __align__(16) float lds2[64 * 68];   // [k][m] (padded)
    const int tid = threadIdx.x;
    const int j0  = blockIdx.x * 16;
    const int jt  = tid & 15;
    const int mt  = tid >> 4;          // m-set {4mt .. 4mt+3}
    float acc[4] = {0.f, 0.f, 0.f, 0.f};

    for (int kc = 0; kc < 512; kc += 64) {
        __syncthreads();
        for (int i = tid; i < 64 * 16; i += 256) {
            const int k = i >> 4, j = i & 15;
            lds1[k * 16 + j] = W_fc1[(size_t)(kc + k) * NB_FC1 + j0 + j];
        }
        for (int i = tid; i < 64 * 64; i += 256) {
            const int k = i & 63, m = i >> 6;
            lds2[k * 68 + m] = (m < 60) ? W_fc2[m * 512 + kc + k] : 0.f;
        }
        __syncthreads();
        for (int k = 0; k < 64; ++k) {
            const float v1 = lds1[k * 16 + jt];
            const floatx4 v2 = *(const floatx4*)&lds2[k * 68 + 4 * mt];
            acc[0] += v2[0] * v1; acc[1] += v2[1] * v1;
            acc[2] += v2[2] * v1; acc[3] += v2[3] * v1;
        }
    }
    #pragma unroll
    for (int s = 0; s < 4; ++s) {
        const int m = 4 * mt + s;
        if (m < 60) Wc[(size_t)m * NB_FC1 + j0 + jt] = (h16)acc[s];
    }
}

// bc = W_fc2 @ b_fc1 + b_fc2   [60] fp32
__global__ void bc_kernel(const float* __restrict__ W_fc2, const float* __restrict__ b_fc1,
                          const float* __restrict__ b_fc2, float* __restrict__ bc)
{
    const int m = blockIdx.x, t = threadIdx.x;
    float p = W_fc2[m * 512 + t] * b_fc1[t] + W_fc2[m * 512 + 256 + t] * b_fc1[256 + t];
    #pragma unroll
    for (int off = 1; off < 64; off <<= 1) p += __shfl_xor(p, off);
    __shared__ float sred[4];
    if ((t & 63) == 0) sred[t >> 6] = p;
    __syncthreads();
    if (t == 0) bc[m] = sred[0] + sred[1] + sred[2] + sred[3] + b_fc2[m];
}

// ---------------------------------------------------------------------------
// out[B,60] = h2flat[B,7680] @ Wc^T + bc.
// ---------------------------------------------------------------------------
__global__ __launch_bounds__(256, 2)
void fc_kernel(const h16* __restrict__ h2,
               const h16* __restrict__ Wc,
               const float* __restrict__ bcv,
               float* __restrict__ out)
{
    __shared__ float red[4][4][16][16];   // [wave][q][row][col]
    const int tid = threadIdx.x;
    const int w = tid >> 6, lane = tid & 63, lrow = lane & 15, lgrp = lane >> 4;
    const size_t base_row = (size_t)blockIdx.x * 16;

    floatx4 acc[4];
    #pragma unroll
    for (int q = 0; q < 4; ++q) acc[q] = floatx4{0.f, 0.f, 0.f, 0.f};

    const h16* arow = h2 + (base_row + lrow) * NB_FC1;
    for (int i = 0; i < 60; ++i) {
        const int kt = w * 60 + i;
        const int k0 = kt * 32 + lgrp * 8;
        const half8 a = *(const half8*)(arow + k0);
        #pragma unroll
        for (int q = 0; q < 4; ++q) {
            const int n = q * 16 + lrow;
            half8 b = 0;
            if (n < 60) b = *(const half8*)(Wc + (size_t)n * NB_FC1 + k0);
            acc[q] = __builtin_amdgcn_mfma_f32_16x16x32_f16(a, b, acc[q], 0, 0, 0);
        }
    }
    #pragma unroll
    for (int q = 0; q < 4; ++q)
        #pragma unroll
        for (int r = 0; r < 4; ++r)
            red[w][q][lgrp * 4 + r][lrow] = acc[q][r];
    __syncthreads();

    #pragma unroll
    for (int s = 0; s < 4; ++s) {
        const int idx = tid + 256 * s;
        const int row = idx >> 6, col = idx & 63;
        if (col < 60) {
            const int q = col >> 4, cin = col & 15;
            const float v = red[0][q][row][cin] + red[1][q][row][cin]
                          + red[2][q][row][cin] + red[3][q][row][cin];
            out[(base_row + row) * 60 + col] = v + bcv[col];
        }
    }
}

extern "C" void kernel_launch(void* const* d_in, const int* in_sizes, int n_in,
                              void* d_out, int out_size, void* d_ws, size_t ws_size,
                              hipStream_t stream)
{
    const float* X      = (const float*)d_in[0];
    const float* W_ih1  = (const float*)d_in[1];
    const float* W_hh1  = (const float*)d_in[2];
    const float* b_ih1  = (const float*)d_in[3];
    const float* b_hh1  = (const float*)d_in[4];
    const float* W_ih2  = (const float*)d_in[5];
    const float* W_hh2  = (const float*)d_in[6];
    const float* b_ih2  = (const float*)d_in[7];
    const float* b_hh2  = (const float*)d_in[8];
    const float* W_fc1  = (const float*)d_in[9];
    const float* b_fc1  = (const float*)d_in[10];
    const float* W_fc2  = (const float*)d_in[11];
    const float* b_fc2  = (const float*)d_in[12];

    // workspace layout: h1 (63MB fp16) | h2 (63MB fp16) | Wc (0.92MB fp16) | bc
    h16* h1 = (h16*)d_ws;
    h16* h2 = h1 + (size_t)4096 * NB_FC1;
    h16* Wc = h2 + (size_t)4096 * NB_FC1;
    float* bc = (float*)(Wc + (size_t)60 * NB_FC1);

    wc_kernel<<<480, 256, 0, stream>>>(W_fc1, W_fc2, Wc);
    bc_kernel<<<60, 256, 0, stream>>>(W_fc2, b_fc1, b_fc2, bc);
    lstm_layer<64,  true ><<<256, 512, 0, stream>>>((const void*)X,  W_ih1, W_hh1, b_ih1, b_hh1, h1);
    lstm_layer<128, false><<<256, 512, 0, stream>>>((const void*)h1, W_ih2, W_hh2, b_ih2, b_hh2, h2);
    fc_kernel<<<256, 256, 0, stream>>>(h2, Wc, bc, (float*)d_out);
}